// Round 11
// baseline (353.449 us; speedup 1.0000x reference)
//
#include <hip/hip_runtime.h>

#define Nn 100000
#define Tt 16
#define Dd 8
#define Hh 40
#define HP1 41
#define NPAIR 1275   // 50*51/2 symmetric pairs (i,j in [0,50))
#define NPADP 1280   // padded to 80 row-tiles of 16
#define NB 128
#define NTILES ((Nn + NB - 1) / NB)   // 782
#define SLAB 20480           // floats per block-slab (1280*16)
#define MAXSLABS 784
#define SLABGRP 32
#define MAXGRP ((MAXSLABS + SLABGRP - 1) / SLABGRP)   // 25
#define WS_WMT 20480         // WMt[41][16], 1024 floats (region 0..20479 unused)
#define WS_PART 21504        // stage-A partials: MAXGRP * SLAB floats
#define WS_SLB (WS_PART + MAXGRP * SLAB)

// output offsets (flat, return order)
#define OFF_BG1   0
#define OFF_BG2   16
#define OFF_MU    32
#define OFF_KAPPA 160
#define OFF_NU    176
#define OFF_PSI   192
#define OFF_WM    1216
#define OFF_WS    1872
#define OFF_ZA    28768
#define OFF_ZB    28784
#define OFF_EA    28800
#define OFF_EB    28816

typedef __attribute__((ext_vector_type(8))) short short8;   // 8 bf16 = 4 VGPR
typedef __attribute__((ext_vector_type(4))) float f32x4;
typedef __attribute__((ext_vector_type(16))) float v16f;

__device__ __forceinline__ int pidx(int i, int j) {
  if (i > j) { int tmp = i; i = j; j = tmp; }
  return (i * (2 * 50 - i + 1)) / 2 + (j - i);
}

__device__ __forceinline__ void decode_pair(int p, int& ii, int& jj) {
  int i = 0, s = 0;
  while (s + (50 - i) <= p) { s += 50 - i; ++i; }
  ii = i; jj = i + (p - s);
}

// xor-swizzled feature tile index: breaks the m/m+8 bank collision for MFMA A reads
__device__ __forceinline__ int xsw(int f, int n) {
  return f * 132 + ((((n >> 3) ^ ((f >> 3) & 3))) << 3) + (n & 7);
}

__device__ __forceinline__ unsigned pk2(float a1, float a0) {
  // (bf16-trunc(a1) << 16) | bf16-trunc(a0) — explicit, perm-semantics-safe
  return (__float_as_uint(a1) & 0xFFFF0000u) | (__float_as_uint(a0) >> 16);
}
__device__ __forceinline__ short8 packhi(float4 a, float4 b) {
  union { unsigned u[4]; short8 s; } r;
  r.u[0] = pk2(a.y, a.x); r.u[1] = pk2(a.w, a.z);
  r.u[2] = pk2(b.y, b.x); r.u[3] = pk2(b.w, b.z);
  return r.s;
}
__device__ __forceinline__ float tr(float x) {
  return __uint_as_float(__float_as_uint(x) & 0xFFFF0000u);
}
__device__ __forceinline__ float4 f4mul(float4 a, float4 b) {
  return make_float4(a.x * b.x, a.y * b.y, a.z * b.z, a.w * b.w);
}
__device__ __forceinline__ float4 f4lo(float4 a) {
  return make_float4(a.x - tr(a.x), a.y - tr(a.y), a.z - tr(a.z), a.w - tr(a.w));
}
__device__ __forceinline__ void fma16v(v16f& A, float p, float4 q0, float4 q1,
                                       float4 q2, float4 q3) {
  A[0]  = fmaf(p, q0.x, A[0]);  A[1]  = fmaf(p, q0.y, A[1]);
  A[2]  = fmaf(p, q0.z, A[2]);  A[3]  = fmaf(p, q0.w, A[3]);
  A[4]  = fmaf(p, q1.x, A[4]);  A[5]  = fmaf(p, q1.y, A[5]);
  A[6]  = fmaf(p, q1.z, A[6]);  A[7]  = fmaf(p, q1.w, A[7]);
  A[8]  = fmaf(p, q2.x, A[8]);  A[9]  = fmaf(p, q2.y, A[9]);
  A[10] = fmaf(p, q2.z, A[10]); A[11] = fmaf(p, q2.w, A[11]);
  A[12] = fmaf(p, q3.x, A[12]); A[13] = fmaf(p, q3.y, A[13]);
  A[14] = fmaf(p, q3.z, A[14]); A[15] = fmaf(p, q3.w, A[15]);
}

// ---------------- Kernel 1: Gram via MFMA: C[1280p x 16t] = P^T * Phi ----------------
__global__ __launch_bounds__(256, 2)
void gram_reduce(const float* __restrict__ Phi, const float* __restrict__ Xd,
                 const float* __restrict__ Yd, const float* __restrict__ Welm,
                 const float* __restrict__ belm, float* __restrict__ slabs)
{
  __shared__ float sW[Dd * Hh];
  __shared__ float sb[Hh];
  __shared__ __align__(16) float XsT[50 * 132];          // swizzled feature-major
  __shared__ __align__(16) unsigned short PhiH[16 * 136]; // phi hi bf16, t-major
  __shared__ __align__(16) unsigned short PhiL[16 * 136]; // phi lo bf16

  int tid = threadIdx.x;
  int lane = tid & 63, wave = tid >> 6;
  int mcol = lane & 15, q = lane >> 4;

  for (int i = tid; i < Dd * Hh; i += 256) sW[i] = Welm[i];
  if (tid < Hh) sb[tid] = belm[tid];

  // per-row-tile packed feature addresses: (f*132)<<2 | ((f>>3)&3)
  int bi[20], bj[20];
#pragma unroll
  for (int T = 0; T < 20; ++T) {
    int p = (wave * 20 + T) * 16 + mcol;
    if (p > NPAIR - 1) p = NPAIR - 1;       // dummy rows: duplicate pair, not flushed
    int i, j; decode_pair(p, i, j);
    bi[T] = ((i * 132) << 2) | ((i >> 3) & 3);
    bj[T] = ((j * 132) << 2) | ((j >> 3) & 3);
  }

  f32x4 acc[20];
#pragma unroll
  for (int T = 0; T < 20; ++T) acc[T] = (f32x4){0.f, 0.f, 0.f, 0.f};

  const float4* Phi4 = (const float4*)Phi;

  for (int tile = blockIdx.x; tile < NTILES; tile += gridDim.x) {
    int n0 = tile * NB;
    __syncthreads();  // protect LDS from prior iteration readers
    // stage phi -> bf16 hi/lo, t-major
    for (int idx = tid; idx < NB * 4; idx += 256) {
      int n = idx >> 2, tq = idx & 3;
      int gn = n0 + n;
      float4 v = (gn < Nn) ? Phi4[(size_t)gn * 4 + tq]
                           : make_float4(0.f, 0.f, 0.f, 0.f);
      float c[4] = {v.x, v.y, v.z, v.w};
#pragma unroll
      for (int cc = 0; cc < 4; ++cc) {
        int t = 4 * tq + cc;
        unsigned ub = __float_as_uint(c[cc]);
        PhiH[t * 136 + n] = (unsigned short)(ub >> 16);
        float lo = c[cc] - __uint_as_float(ub & 0xFFFF0000u);
        PhiL[t * 136 + n] = (unsigned short)(__float_as_uint(lo) >> 16);
      }
    }
    // stage x (transposed, swizzled)
    for (int idx = tid; idx < NB * Dd; idx += 256) {
      int n = idx >> 3, d = idx & 7;
      int gn = n0 + n;
      XsT[xsw(41 + d, n)] = (gn < Nn) ? Xd[(size_t)gn * Dd + d] : 0.f;
    }
    // stage y + const col
    for (int n = tid; n < NB; n += 256) {
      int gn = n0 + n;
      XsT[xsw(49, n)] = (gn < Nn) ? Yd[gn] : 0.f;
      XsT[xsw(40, n)] = (gn < Nn) ? 1.f : 0.f;
    }
    __syncthreads();
    // ELM hidden layer
    for (int idx = tid; idx < NB * Hh; idx += 256) {
      int h = idx >> 7, n = idx & (NB - 1);
      float z = sb[h];
#pragma unroll
      for (int d = 0; d < Dd; ++d) z += XsT[xsw(41 + d, n)] * sW[d * Hh + h];
      float s = 1.f / (1.f + __expf(-z));
      XsT[xsw(h, n)] = (n0 + n < Nn) ? s : 0.f;
    }
    __syncthreads();
    // MFMA K-loop: K = 128 samples, 4 steps of 32
    for (int s = 0; s < 4; ++s) {
      int sb16 = mcol * 136 + 32 * s + 8 * q;
      short8 bh = *(const short8*)(PhiH + sb16);
      short8 bl = *(const short8*)(PhiL + sb16);
      int sq4 = 4 * s + q;
#pragma unroll
      for (int T = 0; T < 20; ++T) {
        int pi = bi[T], pj = bj[T];
        int oi = (pi >> 2) + ((sq4 ^ (pi & 3)) << 3);
        int oj = (pj >> 2) + ((sq4 ^ (pj & 3)) << 3);
        float4 xi0 = *(const float4*)(XsT + oi);
        float4 xi1 = *(const float4*)(XsT + oi + 4);
        float4 xj0 = *(const float4*)(XsT + oj);
        float4 xj1 = *(const float4*)(XsT + oj + 4);
        float4 p0 = f4mul(xi0, xj0), p1 = f4mul(xi1, xj1);
        short8 ah = packhi(p0, p1);
        short8 al = packhi(f4lo(p0), f4lo(p1));
        acc[T] = __builtin_amdgcn_mfma_f32_16x16x32_bf16(ah, bh, acc[T], 0, 0, 0);
        acc[T] = __builtin_amdgcn_mfma_f32_16x16x32_bf16(ah, bl, acc[T], 0, 0, 0);
        acc[T] = __builtin_amdgcn_mfma_f32_16x16x32_bf16(al, bh, acc[T], 0, 0, 0);
        acc[T] = __builtin_amdgcn_mfma_f32_16x16x32_bf16(al, bl, acc[T], 0, 0, 0);
      }
    }
  }
  // flush: D layout col=lane&15 (=t), row=quad*4+reg (=pair within tile)
  float* slab = slabs + (size_t)blockIdx.x * SLAB;
#pragma unroll
  for (int T = 0; T < 20; ++T) {
    int p0 = (wave * 20 + T) * 16 + q * 4;
#pragma unroll
    for (int r = 0; r < 4; ++r) {
      int p = p0 + r;
      if (p < NPAIR) slab[p * Tt + mcol] = acc[T][r];
    }
  }
}

// ---------------- Kernel 1b: slab reduction stage A ----------------
__global__ __launch_bounds__(256)
void reduce_slabs_a(const float* __restrict__ slabs, int nslabs,
                    float* __restrict__ part)
{
  int g = blockIdx.y;
  int idx = blockIdx.x * 256 + threadIdx.x;
  int b0 = g * SLABGRP;
  int b1 = b0 + SLABGRP; if (b1 > nslabs) b1 = nslabs;
  float s = 0.f;
  for (int b = b0; b < b1; ++b) s += slabs[(size_t)b * SLAB + idx];
  part[(size_t)g * SLAB + idx] = s;
}

// ---------------- Kernel 2: per-t inversion + small outputs (reduce-B merged) ----------------
__device__ __forceinline__ float sacc(const float* part, int ngrp, int idx) {
  float s = 0.f;
  for (int g = 0; g < ngrp; ++g) s += part[(size_t)g * SLAB + idx];
  return s;
}

__global__ __launch_bounds__(256)
void finalize_kernel(const float* __restrict__ part, int ngrp,
                     const float* __restrict__ epsA, const float* __restrict__ epsB,
                     const float* __restrict__ zetA, const float* __restrict__ zetB,
                     float* __restrict__ out, float* __restrict__ wmT)
{
  int t = blockIdx.x;
  int tid = threadIdx.x;
  __shared__ float G[HP1][2 * HP1 + 2];
  __shared__ float As[HP1][HP1 + 1];
  __shared__ float bs[HP1];
  __shared__ float colk[HP1];
  __shared__ float red[256];
  __shared__ float wmv[HP1];
  __shared__ float mus[Dd];
  __shared__ float pivinv_s;

  float epsExp = epsA[t] / epsB[t];
  float zetaExp = zetA[t] / zetB[t];

  for (int idx = tid; idx < HP1 * HP1; idx += 256) {
    int i = idx / HP1, j = idx % HP1;
    float a = sacc(part, ngrp, pidx(i, j) * Tt + t);
    As[i][j] = a;
    G[i][j] = epsExp * a + (i == j ? zetaExp : 0.f);
    G[i][HP1 + j] = (i == j) ? 1.f : 0.f;
  }
  if (tid < HP1) bs[tid] = sacc(part, ngrp, pidx(tid, 49) * Tt + t);
  __syncthreads();

  // Gauss-Jordan (SPD, no pivoting)
  for (int k = 0; k < HP1; ++k) {
    if (tid == 0) pivinv_s = 1.f / G[k][k];
    __syncthreads();
    float pivinv = pivinv_s;
    for (int j = tid; j < 2 * HP1; j += 256) G[k][j] *= pivinv;
    if (tid < HP1) colk[tid] = (tid == k) ? 0.f : G[tid][k];
    __syncthreads();
    for (int idx = tid; idx < HP1 * 2 * HP1; idx += 256) {
      int i = idx / (2 * HP1), j = idx % (2 * HP1);
      if (i != k) G[i][j] -= colk[i] * G[k][j];
    }
    __syncthreads();
  }

  for (int idx = tid; idx < HP1 * HP1; idx += 256) {
    int i = idx / HP1, j = idx % HP1;
    out[OFF_WS + (t * HP1 + i) * HP1 + j] = G[i][HP1 + j];
  }
  if (tid < HP1) {
    float s = 0.f;
    for (int j = 0; j < HP1; ++j) s += G[tid][HP1 + j] * bs[j];
    float w = zetaExp * s;
    wmv[tid] = w;
    out[OFF_WM + t * HP1 + tid] = w;
    wmT[tid * Tt + t] = w;
  }
  __syncthreads();
  float lt2 = 0.f;
  for (int idx = tid; idx < HP1 * HP1; idx += 256) {
    int i = idx / HP1, j = idx % HP1;
    lt2 += As[i][j] * G[i][HP1 + j];
  }
  red[tid] = lt2; __syncthreads();
  for (int s = 128; s > 0; s >>= 1) {
    if (tid < s) red[tid] += red[tid + s];
    __syncthreads();
  }
  float t2v = red[0];

  float sp = sacc(part, ngrp, pidx(40, 40) * Tt + t);
  float kap = 1000.f + sp;

  if (tid == 0) {
    float trWS = 0.f, wn = 0.f;
    for (int i = 0; i < HP1; ++i) { trWS += G[i][HP1 + i]; wn += wmv[i] * wmv[i]; }
    out[OFF_BG1 + t] = 1.f + sp;
    float rest = 0.f;
    for (int u = t + 1; u < Tt; ++u) rest += sacc(part, ngrp, pidx(40, 40) * Tt + u);
    out[OFF_BG2 + t] = 1.f + rest;
    out[OFF_KAPPA + t] = kap;
    out[OFF_NU + t] = sp + 100.f;
    out[OFF_ZA + t] = zetA[t] + 0.5f * (float)HP1;
    out[OFF_ZB + t] = zetB[t] + 0.5f * (wn + trWS);
    out[OFF_EA + t] = epsA[t] + 0.5f * sp;
    out[OFF_EB + t] = epsB[t] + 0.5f * t2v;   // resid atomically adds 0.5*t1
  }
  if (tid < Dd) {
    float m = sacc(part, ngrp, pidx(40, 41 + tid) * Tt + t) / kap;
    mus[tid] = m;
    out[OFF_MU + tid * Tt + t] = m;
  }
  __syncthreads();
  if (tid < Dd * Dd) {
    int i = tid / Dd, j = tid % Dd;
    float S = sacc(part, ngrp, pidx(41 + i, 41 + j) * Tt + t);
    float v = (i == j ? 500.f : 0.f) + S - kap * mus[i] * mus[j];
    out[OFF_PSI + (i * Dd + j) * Tt + t] = v;
  }
}

// ---------------- Kernel 3: t1 = sum_n phi*err^2 ----------------
__global__ __launch_bounds__(256)
void resid_kernel(const float* __restrict__ Phi, const float* __restrict__ Xd,
                  const float* __restrict__ Yd, const float* __restrict__ Welm,
                  const float* __restrict__ belm, const float* __restrict__ wmT,
                  float* __restrict__ out)
{
  __shared__ float sWt[Hh][Dd];
  __shared__ float sb[Hh];
  __shared__ __align__(16) float sWM[HP1][Tt];
  __shared__ float red[4][Tt];

  int tid = threadIdx.x;
  for (int i = tid; i < Dd * Hh; i += 256) sWt[i / Dd][i % Dd] = Welm[(i % Dd) * Hh + (i / Dd)];
  if (tid < Hh) sb[tid] = belm[tid];
  for (int i = tid; i < HP1 * Tt; i += 256) sWM[i / Tt][i % Tt] = wmT[i];
  __syncthreads();

  int n = blockIdx.x * 256 + tid;
  v16f acc = {};
  if (n < Nn) {
    const float4* xp = (const float4*)(Xd + (size_t)n * Dd);
    float4 x0 = xp[0], x1 = xp[1];
    float y = Yd[n];
    v16f pred = {};
#pragma unroll 8
    for (int h = 0; h < Hh; ++h) {
      float4 w0 = *(const float4*)&sWt[h][0];
      float4 w1 = *(const float4*)&sWt[h][4];
      float z = sb[h];
      z = fmaf(x0.x, w0.x, z); z = fmaf(x0.y, w0.y, z);
      z = fmaf(x0.z, w0.z, z); z = fmaf(x0.w, w0.w, z);
      z = fmaf(x1.x, w1.x, z); z = fmaf(x1.y, w1.y, z);
      z = fmaf(x1.z, w1.z, z); z = fmaf(x1.w, w1.w, z);
      float s = 1.f / (1.f + __expf(-z));
      const float4* wr = (const float4*)&sWM[h][0];
      fma16v(pred, s, wr[0], wr[1], wr[2], wr[3]);
    }
    {
      const float4* wr = (const float4*)&sWM[40][0];
      fma16v(pred, 1.f, wr[0], wr[1], wr[2], wr[3]);
    }
    const float4* pp = (const float4*)(Phi + (size_t)n * Tt);
    float4 p0 = pp[0], p1 = pp[1], p2 = pp[2], p3 = pp[3];
    float ph[16] = {p0.x,p0.y,p0.z,p0.w, p1.x,p1.y,p1.z,p1.w,
                    p2.x,p2.y,p2.z,p2.w, p3.x,p3.y,p3.z,p3.w};
#pragma unroll
    for (int t = 0; t < Tt; ++t) {
      float e = y - pred[t];
      acc[t] = e * e * ph[t];
    }
  }
#pragma unroll
  for (int t = 0; t < Tt; ++t) {
#pragma unroll
    for (int off = 32; off > 0; off >>= 1) acc[t] += __shfl_down(acc[t], off);
  }
  int wave = tid >> 6, lane = tid & 63;
  if (lane == 0) {
#pragma unroll
    for (int t = 0; t < Tt; ++t) red[wave][t] = acc[t];
  }
  __syncthreads();
  if (tid < Tt) {
    float s = red[0][tid] + red[1][tid] + red[2][tid] + red[3][tid];
    atomicAdd(&out[OFF_EB + tid], 0.5f * s);
  }
}

extern "C" void kernel_launch(void* const* d_in, const int* in_sizes, int n_in,
                              void* d_out, int out_size, void* d_ws, size_t ws_size,
                              hipStream_t stream) {
  const float* Phi = (const float*)d_in[1];
  const float* Xd  = (const float*)d_in[2];
  const float* Yd  = (const float*)d_in[3];
  const float* W   = (const float*)d_in[4];
  const float* bb  = (const float*)d_in[5];
  const float* eA  = (const float*)d_in[6];
  const float* eB  = (const float*)d_in[7];
  const float* zA  = (const float*)d_in[8];
  const float* zB  = (const float*)d_in[9];
  float* out = (float*)d_out;
  float* ws  = (float*)d_ws;

  float* wmT   = ws + WS_WMT;
  float* part  = ws + WS_PART;
  float* slabs = ws + WS_SLB;

  long avail = (long)(ws_size / 4) - WS_SLB;
  int grid1 = (int)(avail / SLAB);
  if (grid1 > NTILES) grid1 = NTILES;
  if (grid1 > MAXSLABS) grid1 = MAXSLABS;
  if (grid1 < 1) grid1 = 1;
  int ngrp = (grid1 + SLABGRP - 1) / SLABGRP;

  hipLaunchKernelGGL(gram_reduce, dim3(grid1), dim3(256), 0, stream, Phi, Xd, Yd, W, bb, slabs);
  hipLaunchKernelGGL(reduce_slabs_a, dim3(SLAB / 256, ngrp), dim3(256), 0, stream, slabs, grid1, part);
  hipLaunchKernelGGL(finalize_kernel, dim3(Tt), dim3(256), 0, stream, part, ngrp, eA, eB, zA, zB, out, wmT);
  hipLaunchKernelGGL(resid_kernel, dim3((Nn + 255) / 256), dim3(256), 0, stream, Phi, Xd, Yd, W, bb, wmT, out);
}

// Round 12
// 262.599 us; speedup vs baseline: 1.3460x; 1.3460x over previous
//
#include <hip/hip_runtime.h>

#define Nn 100000
#define Tt 16
#define Dd 8
#define Hh 40
#define HP1 41
#define XSD 51     // Xs row: [h0..h39, 1, x0..x7, y, 0pad] stride 51
#define NPAIR 1275 // 50*51/2 symmetric pairs (i,j in [0,50))
#define NB 128
#define NTILES ((Nn + NB - 1) / NB)   // 782
#define SLAB 20480           // floats per block-slab (NPAIR*16 = 20400, padded)
#define MAXSLABS 784
#define SLABGRP 32           // slabs per stage-A group
#define MAXGRP ((MAXSLABS + SLABGRP - 1) / SLABGRP)   // 25
#define WS_ACC 0             // acc_red: 20480 floats
#define WS_WMT 20480         // WMt[41][16] transposed WM, 1024 floats
#define WS_PART 21504        // stage-A partials: MAXGRP * SLAB floats
#define WS_SLB (WS_PART + MAXGRP * SLAB)              // slabs start here

// output offsets (flat, return order)
#define OFF_BG1   0
#define OFF_BG2   16
#define OFF_MU    32
#define OFF_KAPPA 160
#define OFF_NU    176
#define OFF_PSI   192
#define OFF_WM    1216
#define OFF_WS    1872
#define OFF_ZA    28768
#define OFF_ZB    28784
#define OFF_EA    28800
#define OFF_EB    28816

typedef float v16f __attribute__((ext_vector_type(16)));

__device__ __forceinline__ int pidx(int i, int j) {
  if (i > j) { int tmp = i; i = j; j = tmp; }
  return (i * (2 * 50 - i + 1)) / 2 + (j - i);
}

__device__ __forceinline__ void fma16(v16f& A, float p, float4 q0, float4 q1,
                                      float4 q2, float4 q3) {
  A[0]  = fmaf(p, q0.x, A[0]);  A[1]  = fmaf(p, q0.y, A[1]);
  A[2]  = fmaf(p, q0.z, A[2]);  A[3]  = fmaf(p, q0.w, A[3]);
  A[4]  = fmaf(p, q1.x, A[4]);  A[5]  = fmaf(p, q1.y, A[5]);
  A[6]  = fmaf(p, q1.z, A[6]);  A[7]  = fmaf(p, q1.w, A[7]);
  A[8]  = fmaf(p, q2.x, A[8]);  A[9]  = fmaf(p, q2.y, A[9]);
  A[10] = fmaf(p, q2.z, A[10]); A[11] = fmaf(p, q2.w, A[11]);
  A[12] = fmaf(p, q3.x, A[12]); A[13] = fmaf(p, q3.y, A[13]);
  A[14] = fmaf(p, q3.z, A[14]); A[15] = fmaf(p, q3.w, A[15]);
}

// ---------------- Kernel 1: weighted Gram reduction (R8 version: 2x3 tile, LDS phi) ----------------
__global__ __launch_bounds__(256, 3)
void gram_reduce(const float* __restrict__ Phi, const float* __restrict__ Xd,
                 const float* __restrict__ Yd, const float* __restrict__ Welm,
                 const float* __restrict__ belm, float* __restrict__ slabs)
{
  __shared__ float sW[Dd * Hh];
  __shared__ float sb[Hh];
  __shared__ float Xs[NB][XSD];
  __shared__ __align__(16) float Ps[NB][Tt];   // phi tile, row = 64B

  int tid = threadIdx.x;
  for (int i = tid; i < Dd * Hh; i += 256) sW[i] = Welm[i];
  if (tid < Hh) sb[tid] = belm[tid];

  // ---- decode thread -> 2x3 tile (rp: row-pair 0..24, cq: col-triple) ----
  int rp = -1, cq = 0;
  {
    int c = 0;
    for (int r = 0; r < 25; ++r) {
      int cmin = (2 * r) / 3;
      int cnt = 17 - cmin;          // cq in [cmin, 17)
      if (rp < 0 && tid < c + cnt) { rp = r; cq = cmin + (tid - c); }
      c += cnt;
    }
    if (tid >= c) rp = -1;          // 233 active threads
  }
  bool active = (rp >= 0);
  int r0 = 2 * rp, r1 = 2 * rp + 1;
  int c0 = 3 * cq, c1 = 3 * cq + 1, c2 = 3 * cq + 2;
  if (!active) { r0 = r1 = 0; c0 = c1 = c2 = 0; }

  v16f A00 = {}, A01 = {}, A02 = {}, A10 = {}, A11 = {}, A12 = {};

  for (int tile = blockIdx.x; tile < NTILES; tile += gridDim.x) {
    int n0 = tile * NB;
    __syncthreads();  // protect Xs/Ps from prior iteration readers
    // stage phi (coalesced float4 copy; layout matches global)
    for (int idx = tid; idx < NB * Tt / 4; idx += 256) {
      int n = idx / 4, q = idx % 4;
      int gn = n0 + n;
      ((float4*)&Ps[n][0])[q] = (gn < Nn)
        ? ((const float4*)(Phi + (size_t)gn * Tt))[q]
        : make_float4(0.f, 0.f, 0.f, 0.f);
    }
    // stage x
    for (int idx = tid; idx < NB * Dd; idx += 256) {
      int n = idx / Dd, d = idx % Dd;
      int gn = n0 + n;
      Xs[n][41 + d] = (gn < Nn) ? Xd[gn * Dd + d] : 0.f;
    }
    // stage y + const col + pad col
    for (int n = tid; n < NB; n += 256) {
      int gn = n0 + n;
      Xs[n][49] = (gn < Nn) ? Yd[gn] : 0.f;
      Xs[n][40] = (gn < Nn) ? 1.f : 0.f;
      Xs[n][50] = 0.f;
    }
    __syncthreads();
    // ELM hidden layer: h = sigmoid(x W + b); zero for pad rows
    for (int idx = tid; idx < NB * Hh; idx += 256) {
      int n = idx / Hh, h = idx % Hh;
      float z = sb[h];
#pragma unroll
      for (int d = 0; d < Dd; ++d) z += Xs[n][41 + d] * sW[d * Hh + h];
      float s = 1.f / (1.f + __expf(-z));
      Xs[n][h] = (n0 + n < Nn) ? s : 0.f;
    }
    __syncthreads();
    // accumulate: A[r][c][t] += phi[n][t] * Xe[n][r] * Xe[n][c]
    if (active) {
#pragma unroll 2
      for (int n = 0; n < NB; ++n) {
        const float4* pr = (const float4*)&Ps[n][0];   // LDS broadcast b128 x4
        float4 q0 = pr[0], q1 = pr[1], q2 = pr[2], q3 = pr[3];
        float xi0 = Xs[n][r0], xi1 = Xs[n][r1];
        float xj0 = Xs[n][c0], xj1 = Xs[n][c1], xj2 = Xs[n][c2];
        fma16(A00, xi0 * xj0, q0, q1, q2, q3);
        fma16(A01, xi0 * xj1, q0, q1, q2, q3);
        fma16(A02, xi0 * xj2, q0, q1, q2, q3);
        fma16(A10, xi1 * xj0, q0, q1, q2, q3);
        fma16(A11, xi1 * xj1, q0, q1, q2, q3);
        fma16(A12, xi1 * xj2, q0, q1, q2, q3);
      }
    }
  }
  // flush: 64B vector store per upper-triangle pair
  float* slab = slabs + (size_t)blockIdx.x * SLAB;
  if (active) {
    if (c0 >= r0 && c0 < 50) *(v16f*)(slab + pidx(r0, c0) * Tt) = A00;
    if (c1 >= r0 && c1 < 50) *(v16f*)(slab + pidx(r0, c1) * Tt) = A01;
    if (c2 >= r0 && c2 < 50) *(v16f*)(slab + pidx(r0, c2) * Tt) = A02;
    if (c0 >= r1 && c0 < 50) *(v16f*)(slab + pidx(r1, c0) * Tt) = A10;
    if (c1 >= r1 && c1 < 50) *(v16f*)(slab + pidx(r1, c1) * Tt) = A11;
    if (c2 >= r1 && c2 < 50) *(v16f*)(slab + pidx(r1, c2) * Tt) = A12;
  }
}

// ---------------- Kernel 1b: two-stage slab reduction (no atomics) ----------------
__global__ __launch_bounds__(256)
void reduce_slabs_a(const float* __restrict__ slabs, int nslabs,
                    float* __restrict__ part)
{
  int g = blockIdx.y;
  int idx = blockIdx.x * 256 + threadIdx.x;   // 80 blocks cover SLAB
  int b0 = g * SLABGRP;
  int b1 = b0 + SLABGRP; if (b1 > nslabs) b1 = nslabs;
  float s = 0.f;
  for (int b = b0; b < b1; ++b) s += slabs[(size_t)b * SLAB + idx];
  part[(size_t)g * SLAB + idx] = s;
}

__global__ __launch_bounds__(256)
void reduce_slabs_b(const float* __restrict__ part, int ngrp,
                    float* __restrict__ accout)
{
  int idx = blockIdx.x * 256 + threadIdx.x;
  float s = 0.f;
  for (int g = 0; g < ngrp; ++g) s += part[(size_t)g * SLAB + idx];
  accout[idx] = s;
}

// ---------------- Kernel 2: wave-per-t Gauss-Jordan + all small outputs ----------------
// 16 blocks x 64 threads: single-wave GJ, float4 LDS rows, cheap single-wave barriers.
__global__ __launch_bounds__(64)
void finalize_kernel(const float* __restrict__ acc, const float* __restrict__ epsA,
                     const float* __restrict__ epsB, const float* __restrict__ zetA,
                     const float* __restrict__ zetB, float* __restrict__ out,
                     float* __restrict__ wmT)
{
  int t = blockIdx.x;
  int lane = threadIdx.x;
  __shared__ __align__(16) float G[HP1][84];   // [M | I] -> [junk | inv], 21 float4/row
  __shared__ float As[HP1][HP1 + 1];
  __shared__ float bs[HP1];
  __shared__ float wmv[HP1];
  __shared__ float mus[Dd];

  float epsExp = epsA[t] / epsB[t];
  float zetaExp = zetA[t] / zetB[t];

  for (int idx = lane; idx < HP1 * HP1; idx += 64) {
    int i = idx / HP1, j = idx % HP1;
    float a = acc[pidx(i, j) * Tt + t];
    As[i][j] = a;
    G[i][j] = epsExp * a + (i == j ? zetaExp : 0.f);
  }
  for (int idx = lane; idx < HP1 * 43; idx += 64) {    // cols 41..83 (incl pad)
    int i = idx / 43, j = 41 + idx % 43;
    G[i][j] = (j == 41 + i) ? 1.f : 0.f;
  }
  if (lane < HP1) bs[lane] = acc[pidx(lane, 49) * Tt + t];
  __syncthreads();

  float4* G4 = (float4*)&G[0][0];   // row stride 21 float4
  for (int k = 0; k < HP1; ++k) {
    float pivinv = 1.f / G[k][k];   // broadcast read (stable since last barrier)
    __syncthreads();
    if (lane < 21) {                // scale row k
      float4 v = G4[k * 21 + lane];
      v.x *= pivinv; v.y *= pivinv; v.z *= pivinv; v.w *= pivinv;
      G4[k * 21 + lane] = v;
    }
    __syncthreads();
    if (lane < HP1 && lane != k) {  // lane = row
      float f = G[lane][k];
#pragma unroll
      for (int c = 0; c < 21; ++c) {
        float4 rk = G4[k * 21 + c];       // broadcast
        float4 v  = G4[lane * 21 + c];
        v.x = fmaf(-f, rk.x, v.x); v.y = fmaf(-f, rk.y, v.y);
        v.z = fmaf(-f, rk.z, v.z); v.w = fmaf(-f, rk.w, v.w);
        G4[lane * 21 + c] = v;
      }
    }
    __syncthreads();
  }

  // write WS (inverse sits at cols 41..81)
  for (int idx = lane; idx < HP1 * HP1; idx += 64) {
    int i = idx / HP1, j = idx % HP1;
    out[OFF_WS + (t * HP1 + i) * HP1 + j] = G[i][41 + j];
  }
  // WMv = zetaExp * WS @ b
  if (lane < HP1) {
    float s = 0.f;
    for (int j = 0; j < HP1; ++j) s += G[lane][41 + j] * bs[j];
    float w = zetaExp * s;
    wmv[lane] = w;
    out[OFF_WM + t * HP1 + lane] = w;
    wmT[lane * Tt + t] = w;
  }
  __syncthreads();
  // t2 = sum_ij A_ij * WS_ij
  float lt2 = 0.f;
  for (int idx = lane; idx < HP1 * HP1; idx += 64) {
    int i = idx / HP1, j = idx % HP1;
    lt2 += As[i][j] * G[i][41 + j];
  }
#pragma unroll
  for (int off = 32; off > 0; off >>= 1) lt2 += __shfl_down(lt2, off);
  float t2v = __shfl(lt2, 0);

  float sp = acc[pidx(40, 40) * Tt + t];  // sumPhi[t]
  float kap = 1000.f + sp;

  if (lane == 0) {
    float trWS = 0.f, wn = 0.f;
    for (int i = 0; i < HP1; ++i) { trWS += G[i][41 + i]; wn += wmv[i] * wmv[i]; }
    out[OFF_BG1 + t] = 1.f + sp;
    float rest = 0.f;
    for (int u = t + 1; u < Tt; ++u) rest += acc[pidx(40, 40) * Tt + u];
    out[OFF_BG2 + t] = 1.f + rest;            // ALPHA_DP = 1
    out[OFF_KAPPA + t] = kap;
    out[OFF_NU + t] = sp + 100.f;             // sumPhi + NU0
    out[OFF_ZA + t] = zetA[t] + 0.5f * (float)HP1;
    out[OFF_ZB + t] = zetB[t] + 0.5f * (wn + trWS);
    out[OFF_EA + t] = epsA[t] + 0.5f * sp;
    out[OFF_EB + t] = epsB[t] + 0.5f * t2v;   // resid atomically adds 0.5*t1
  }
  // mu
  if (lane < Dd) {
    float m = acc[pidx(40, 41 + lane) * Tt + t] / kap;
    mus[lane] = m;
    out[OFF_MU + lane * Tt + t] = m;
  }
  __syncthreads();
  // psi = 500*I + S - kappa * mu mu^T
  if (lane < Dd * Dd) {
    int i = lane / Dd, j = lane % Dd;
    float S = acc[pidx(41 + i, 41 + j) * Tt + t];
    float v = (i == j ? 500.f : 0.f) + S - kap * mus[i] * mus[j];
    out[OFF_PSI + (i * Dd + j) * Tt + t] = v;
  }
}

// ---------------- Kernel 3: t1 = sum_n phi*err^2 (one thread per n) ----------------
__global__ __launch_bounds__(256)
void resid_kernel(const float* __restrict__ Phi, const float* __restrict__ Xd,
                  const float* __restrict__ Yd, const float* __restrict__ Welm,
                  const float* __restrict__ belm, const float* __restrict__ wmT,
                  float* __restrict__ out)
{
  __shared__ float sWt[Hh][Dd];   // transposed ELM weights: sWt[h][d]
  __shared__ float sb[Hh];
  __shared__ __align__(16) float sWM[HP1][Tt];   // WM rows, broadcast b128 reads
  __shared__ float red[4][Tt];

  int tid = threadIdx.x;
  for (int i = tid; i < Dd * Hh; i += 256) sWt[i / Dd][i % Dd] = Welm[(i % Dd) * Hh + (i / Dd)];
  if (tid < Hh) sb[tid] = belm[tid];
  for (int i = tid; i < HP1 * Tt; i += 256) sWM[i / Tt][i % Tt] = wmT[i];
  __syncthreads();

  int n = blockIdx.x * 256 + tid;
  v16f acc = {};
  if (n < Nn) {
    const float4* xp = (const float4*)(Xd + (size_t)n * Dd);
    float4 x0 = xp[0], x1 = xp[1];
    float y = Yd[n];
    v16f pred = {};
#pragma unroll 8
    for (int h = 0; h < Hh; ++h) {
      float4 w0 = *(const float4*)&sWt[h][0];
      float4 w1 = *(const float4*)&sWt[h][4];
      float z = sb[h];
      z = fmaf(x0.x, w0.x, z); z = fmaf(x0.y, w0.y, z);
      z = fmaf(x0.z, w0.z, z); z = fmaf(x0.w, w0.w, z);
      z = fmaf(x1.x, w1.x, z); z = fmaf(x1.y, w1.y, z);
      z = fmaf(x1.z, w1.z, z); z = fmaf(x1.w, w1.w, z);
      float s = 1.f / (1.f + __expf(-z));
      const float4* wr = (const float4*)&sWM[h][0];   // LDS broadcast
      fma16(pred, s, wr[0], wr[1], wr[2], wr[3]);
    }
    { // bias feature (value 1) -> add WM row 40
      const float4* wr = (const float4*)&sWM[40][0];
      fma16(pred, 1.f, wr[0], wr[1], wr[2], wr[3]);
    }
    const float4* pp = (const float4*)(Phi + (size_t)n * Tt);
    float4 p0 = pp[0], p1 = pp[1], p2 = pp[2], p3 = pp[3];
    float ph[16] = {p0.x,p0.y,p0.z,p0.w, p1.x,p1.y,p1.z,p1.w,
                    p2.x,p2.y,p2.z,p2.w, p3.x,p3.y,p3.z,p3.w};
#pragma unroll
    for (int t = 0; t < Tt; ++t) {
      float e = y - pred[t];
      acc[t] = e * e * ph[t];
    }
  }
  // wave shuffle reduction, then cross-wave via LDS
#pragma unroll
  for (int t = 0; t < Tt; ++t) {
#pragma unroll
    for (int off = 32; off > 0; off >>= 1) acc[t] += __shfl_down(acc[t], off);
  }
  int wave = tid >> 6, lane = tid & 63;
  if (lane == 0) {
#pragma unroll
    for (int t = 0; t < Tt; ++t) red[wave][t] = acc[t];
  }
  __syncthreads();
  if (tid < Tt) {
    float s = red[0][tid] + red[1][tid] + red[2][tid] + red[3][tid];
    atomicAdd(&out[OFF_EB + tid], 0.5f * s);
  }
}

extern "C" void kernel_launch(void* const* d_in, const int* in_sizes, int n_in,
                              void* d_out, int out_size, void* d_ws, size_t ws_size,
                              hipStream_t stream) {
  const float* Phi = (const float*)d_in[1];
  const float* Xd  = (const float*)d_in[2];
  const float* Yd  = (const float*)d_in[3];
  const float* W   = (const float*)d_in[4];
  const float* bb  = (const float*)d_in[5];
  const float* eA  = (const float*)d_in[6];
  const float* eB  = (const float*)d_in[7];
  const float* zA  = (const float*)d_in[8];
  const float* zB  = (const float*)d_in[9];
  float* out = (float*)d_out;
  float* ws  = (float*)d_ws;

  float* acc_red = ws + WS_ACC;
  float* wmT     = ws + WS_WMT;
  float* part    = ws + WS_PART;
  float* slabs   = ws + WS_SLB;

  // slab count bounded by available scratch (deterministic, graph-safe)
  long avail = (long)(ws_size / 4) - WS_SLB;
  int grid1 = (int)(avail / SLAB);
  if (grid1 > NTILES) grid1 = NTILES;       // 782: one tile per block
  if (grid1 > MAXSLABS) grid1 = MAXSLABS;
  if (grid1 < 1) grid1 = 1;
  int ngrp = (grid1 + SLABGRP - 1) / SLABGRP;

  hipLaunchKernelGGL(gram_reduce, dim3(grid1), dim3(256), 0, stream, Phi, Xd, Yd, W, bb, slabs);
  hipLaunchKernelGGL(reduce_slabs_a, dim3(SLAB / 256, ngrp), dim3(256), 0, stream, slabs, grid1, part);
  hipLaunchKernelGGL(reduce_slabs_b, dim3(SLAB / 256), dim3(256), 0, stream, part, ngrp, acc_red);
  hipLaunchKernelGGL(finalize_kernel, dim3(Tt), dim3(64), 0, stream, acc_red, eA, eB, zA, zB, out, wmT);
  hipLaunchKernelGGL(resid_kernel, dim3((Nn + 255) / 256), dim3(256), 0, stream, Phi, Xd, Yd, W, bb, wmT, out);
}

// Round 13
// 241.146 us; speedup vs baseline: 1.4657x; 1.0890x over previous
//
#include <hip/hip_runtime.h>

#define Nn 100000
#define Tt 16
#define Dd 8
#define Hh 40
#define HP1 41
#define XSD 51     // Xs row: [h0..h39, 1, x0..x7, y, 0pad] stride 51
#define NPAIR 1275 // 50*51/2 symmetric pairs (i,j in [0,50))
#define NB 128
#define NTILES ((Nn + NB - 1) / NB)   // 782
#define SLAB 20480           // floats per block-slab (NPAIR*16 = 20400, padded)
#define MAXSLABS 784
#define SLABGRP 32           // slabs per stage-A group
#define MAXGRP ((MAXSLABS + SLABGRP - 1) / SLABGRP)   // 25
#define WS_ACC 0             // acc_red: 20480 floats
#define WS_WMT 20480         // WMt[41][16] transposed WM, 1024 floats
#define WS_PART 21504        // stage-A partials: MAXGRP * SLAB floats
#define WS_SLB (WS_PART + MAXGRP * SLAB)              // slabs start here

// output offsets (flat, return order)
#define OFF_BG1   0
#define OFF_BG2   16
#define OFF_MU    32
#define OFF_KAPPA 160
#define OFF_NU    176
#define OFF_PSI   192
#define OFF_WM    1216
#define OFF_WS    1872
#define OFF_ZA    28768
#define OFF_ZB    28784
#define OFF_EA    28800
#define OFF_EB    28816

typedef float v16f __attribute__((ext_vector_type(16)));

__device__ __forceinline__ int pidx(int i, int j) {
  if (i > j) { int tmp = i; i = j; j = tmp; }
  return (i * (2 * 50 - i + 1)) / 2 + (j - i);
}

__device__ __forceinline__ void fma16(v16f& A, float p, float4 q0, float4 q1,
                                      float4 q2, float4 q3) {
  A[0]  = fmaf(p, q0.x, A[0]);  A[1]  = fmaf(p, q0.y, A[1]);
  A[2]  = fmaf(p, q0.z, A[2]);  A[3]  = fmaf(p, q0.w, A[3]);
  A[4]  = fmaf(p, q1.x, A[4]);  A[5]  = fmaf(p, q1.y, A[5]);
  A[6]  = fmaf(p, q1.z, A[6]);  A[7]  = fmaf(p, q1.w, A[7]);
  A[8]  = fmaf(p, q2.x, A[8]);  A[9]  = fmaf(p, q2.y, A[9]);
  A[10] = fmaf(p, q2.z, A[10]); A[11] = fmaf(p, q2.w, A[11]);
  A[12] = fmaf(p, q3.x, A[12]); A[13] = fmaf(p, q3.y, A[13]);
  A[14] = fmaf(p, q3.z, A[14]); A[15] = fmaf(p, q3.w, A[15]);
}

// ---------------- Kernel 1: weighted Gram reduction (R8 version: 2x3 tile, LDS phi) ----------------
__global__ __launch_bounds__(256, 3)
void gram_reduce(const float* __restrict__ Phi, const float* __restrict__ Xd,
                 const float* __restrict__ Yd, const float* __restrict__ Welm,
                 const float* __restrict__ belm, float* __restrict__ slabs)
{
  __shared__ float sW[Dd * Hh];
  __shared__ float sb[Hh];
  __shared__ float Xs[NB][XSD];
  __shared__ __align__(16) float Ps[NB][Tt];   // phi tile, row = 64B

  int tid = threadIdx.x;
  for (int i = tid; i < Dd * Hh; i += 256) sW[i] = Welm[i];
  if (tid < Hh) sb[tid] = belm[tid];

  // ---- decode thread -> 2x3 tile (rp: row-pair 0..24, cq: col-triple) ----
  int rp = -1, cq = 0;
  {
    int c = 0;
    for (int r = 0; r < 25; ++r) {
      int cmin = (2 * r) / 3;
      int cnt = 17 - cmin;          // cq in [cmin, 17)
      if (rp < 0 && tid < c + cnt) { rp = r; cq = cmin + (tid - c); }
      c += cnt;
    }
    if (tid >= c) rp = -1;          // 233 active threads
  }
  bool active = (rp >= 0);
  int r0 = 2 * rp, r1 = 2 * rp + 1;
  int c0 = 3 * cq, c1 = 3 * cq + 1, c2 = 3 * cq + 2;
  if (!active) { r0 = r1 = 0; c0 = c1 = c2 = 0; }

  v16f A00 = {}, A01 = {}, A02 = {}, A10 = {}, A11 = {}, A12 = {};

  for (int tile = blockIdx.x; tile < NTILES; tile += gridDim.x) {
    int n0 = tile * NB;
    __syncthreads();  // protect Xs/Ps from prior iteration readers
    // stage phi (coalesced float4 copy; layout matches global)
    for (int idx = tid; idx < NB * Tt / 4; idx += 256) {
      int n = idx / 4, q = idx % 4;
      int gn = n0 + n;
      ((float4*)&Ps[n][0])[q] = (gn < Nn)
        ? ((const float4*)(Phi + (size_t)gn * Tt))[q]
        : make_float4(0.f, 0.f, 0.f, 0.f);
    }
    // stage x
    for (int idx = tid; idx < NB * Dd; idx += 256) {
      int n = idx / Dd, d = idx % Dd;
      int gn = n0 + n;
      Xs[n][41 + d] = (gn < Nn) ? Xd[gn * Dd + d] : 0.f;
    }
    // stage y + const col + pad col
    for (int n = tid; n < NB; n += 256) {
      int gn = n0 + n;
      Xs[n][49] = (gn < Nn) ? Yd[gn] : 0.f;
      Xs[n][40] = (gn < Nn) ? 1.f : 0.f;
      Xs[n][50] = 0.f;
    }
    __syncthreads();
    // ELM hidden layer: h = sigmoid(x W + b); zero for pad rows
    for (int idx = tid; idx < NB * Hh; idx += 256) {
      int n = idx / Hh, h = idx % Hh;
      float z = sb[h];
#pragma unroll
      for (int d = 0; d < Dd; ++d) z += Xs[n][41 + d] * sW[d * Hh + h];
      float s = 1.f / (1.f + __expf(-z));
      Xs[n][h] = (n0 + n < Nn) ? s : 0.f;
    }
    __syncthreads();
    // accumulate: A[r][c][t] += phi[n][t] * Xe[n][r] * Xe[n][c]
    if (active) {
#pragma unroll 2
      for (int n = 0; n < NB; ++n) {
        const float4* pr = (const float4*)&Ps[n][0];   // LDS broadcast b128 x4
        float4 q0 = pr[0], q1 = pr[1], q2 = pr[2], q3 = pr[3];
        float xi0 = Xs[n][r0], xi1 = Xs[n][r1];
        float xj0 = Xs[n][c0], xj1 = Xs[n][c1], xj2 = Xs[n][c2];
        fma16(A00, xi0 * xj0, q0, q1, q2, q3);
        fma16(A01, xi0 * xj1, q0, q1, q2, q3);
        fma16(A02, xi0 * xj2, q0, q1, q2, q3);
        fma16(A10, xi1 * xj0, q0, q1, q2, q3);
        fma16(A11, xi1 * xj1, q0, q1, q2, q3);
        fma16(A12, xi1 * xj2, q0, q1, q2, q3);
      }
    }
  }
  // flush: 64B vector store per upper-triangle pair
  float* slab = slabs + (size_t)blockIdx.x * SLAB;
  if (active) {
    if (c0 >= r0 && c0 < 50) *(v16f*)(slab + pidx(r0, c0) * Tt) = A00;
    if (c1 >= r0 && c1 < 50) *(v16f*)(slab + pidx(r0, c1) * Tt) = A01;
    if (c2 >= r0 && c2 < 50) *(v16f*)(slab + pidx(r0, c2) * Tt) = A02;
    if (c0 >= r1 && c0 < 50) *(v16f*)(slab + pidx(r1, c0) * Tt) = A10;
    if (c1 >= r1 && c1 < 50) *(v16f*)(slab + pidx(r1, c1) * Tt) = A11;
    if (c2 >= r1 && c2 < 50) *(v16f*)(slab + pidx(r1, c2) * Tt) = A12;
  }
}

// ---------------- Kernel 1b: two-stage slab reduction (no atomics) ----------------
__global__ __launch_bounds__(256)
void reduce_slabs_a(const float* __restrict__ slabs, int nslabs,
                    float* __restrict__ part)
{
  int g = blockIdx.y;
  int idx = blockIdx.x * 256 + threadIdx.x;   // 80 blocks cover SLAB
  int b0 = g * SLABGRP;
  int b1 = b0 + SLABGRP; if (b1 > nslabs) b1 = nslabs;
  float s = 0.f;
  for (int b = b0; b < b1; ++b) s += slabs[(size_t)b * SLAB + idx];
  part[(size_t)g * SLAB + idx] = s;
}

__global__ __launch_bounds__(256)
void reduce_slabs_b(const float* __restrict__ part, int ngrp,
                    float* __restrict__ accout)
{
  int idx = blockIdx.x * 256 + threadIdx.x;
  float s = 0.f;
  for (int g = 0; g < ngrp; ++g) s += part[(size_t)g * SLAB + idx];
  accout[idx] = s;
}

// ---------------- Kernel 2: in-register wave GJ (no LDS/barriers in pivot loop) ----------------
// 16 blocks x 64 threads. lane = row; full augmented row [M | I] (84 cols) in VGPRs.
// Pivot row broadcast via __shfl (uniform k -> v_readlane); piv/f via constant-index selects.
__global__ __launch_bounds__(64)
void finalize_kernel(const float* __restrict__ acc, const float* __restrict__ epsA,
                     const float* __restrict__ epsB, const float* __restrict__ zetA,
                     const float* __restrict__ zetB, float* __restrict__ out,
                     float* __restrict__ wmT)
{
  int t = blockIdx.x;
  int lane = threadIdx.x;
  __shared__ float As[HP1][HP1 + 1];
  __shared__ float bs[HP1];
  __shared__ float mus[Dd];

  float epsExp = epsA[t] / epsB[t];
  float zetaExp = zetA[t] / zetB[t];

  // stage A (symmetric, expanded) into LDS
  for (int idx = lane; idx < HP1 * HP1; idx += 64) {
    int i = idx / HP1, j = idx % HP1;
    As[i][j] = acc[pidx(i, j) * Tt + t];
  }
  if (lane < HP1) bs[lane] = acc[pidx(lane, 49) * Tt + t];
  __syncthreads();

  // per-lane augmented row in registers: cols 0..40 = M, 41..81 = I
  float row[82];
#pragma unroll
  for (int c = 0; c < 82; ++c) row[c] = 0.f;
  if (lane < HP1) {
    for (int j = 0; j < HP1; ++j)
      row[j] = epsExp * As[lane][j] + (lane == j ? zetaExp : 0.f);
    row[41 + lane] = 1.f;
  }

  // Gauss-Jordan: k-loop rolled (I-cache), c-loops unrolled (registers)
  for (int k = 0; k < HP1; ++k) {
    float rk[82];
    float piv = 1.f, f = 0.f;
#pragma unroll
    for (int c = 0; c < 82; ++c) {
      rk[c] = __shfl(row[c], k);          // uniform k -> readlane broadcast
      if (c < HP1 && c == k) { piv = rk[c]; f = row[c]; }
    }
    float pivinv = 1.f / piv;
    float g = (lane == k) ? (piv - 1.f) : f;   // pivot row maps to rk/piv
#pragma unroll
    for (int c = 0; c < 82; ++c) {
      row[c] = fmaf(-g, rk[c] * pivinv, row[c]);
    }
  }

  // write WS (inverse at cols 41..81)
  if (lane < HP1) {
    for (int j = 0; j < HP1; ++j)
      out[OFF_WS + (t * HP1 + lane) * HP1 + j] = row[41 + j];
  }
  // WMv = zetaExp * WS @ b ; per-lane scalars for reductions
  float w = 0.f, lt2 = 0.f, trc = 0.f;
  if (lane < HP1) {
    float s = 0.f;
    for (int j = 0; j < HP1; ++j) s += row[41 + j] * bs[j];
    w = zetaExp * s;
    out[OFF_WM + t * HP1 + lane] = w;
    wmT[lane * Tt + t] = w;
    for (int j = 0; j < HP1; ++j) lt2 += As[lane][j] * row[41 + j];
    trc = row[41 + lane];
  }
  float wn = w * w;
#pragma unroll
  for (int off = 32; off > 0; off >>= 1) {
    lt2 += __shfl_down(lt2, off);
    wn  += __shfl_down(wn, off);
    trc += __shfl_down(trc, off);
  }

  float sp = acc[pidx(40, 40) * Tt + t];  // sumPhi[t]
  float kap = 1000.f + sp;

  if (lane == 0) {
    out[OFF_BG1 + t] = 1.f + sp;
    float rest = 0.f;
    for (int u = t + 1; u < Tt; ++u) rest += acc[pidx(40, 40) * Tt + u];
    out[OFF_BG2 + t] = 1.f + rest;            // ALPHA_DP = 1
    out[OFF_KAPPA + t] = kap;
    out[OFF_NU + t] = sp + 100.f;             // sumPhi + NU0
    out[OFF_ZA + t] = zetA[t] + 0.5f * (float)HP1;
    out[OFF_ZB + t] = zetB[t] + 0.5f * (wn + trc);
    out[OFF_EA + t] = epsA[t] + 0.5f * sp;
    out[OFF_EB + t] = epsB[t] + 0.5f * lt2;   // resid atomically adds 0.5*t1
  }
  // mu
  if (lane < Dd) {
    float m = acc[pidx(40, 41 + lane) * Tt + t] / kap;
    mus[lane] = m;
    out[OFF_MU + lane * Tt + t] = m;
  }
  __syncthreads();
  // psi = 500*I + S - kappa * mu mu^T
  if (lane < Dd * Dd) {
    int i = lane / Dd, j = lane % Dd;
    float S = acc[pidx(41 + i, 41 + j) * Tt + t];
    float v = (i == j ? 500.f : 0.f) + S - kap * mus[i] * mus[j];
    out[OFF_PSI + (i * Dd + j) * Tt + t] = v;
  }
}

// ---------------- Kernel 3: t1 = sum_n phi*err^2 (one thread per n) ----------------
__global__ __launch_bounds__(256)
void resid_kernel(const float* __restrict__ Phi, const float* __restrict__ Xd,
                  const float* __restrict__ Yd, const float* __restrict__ Welm,
                  const float* __restrict__ belm, const float* __restrict__ wmT,
                  float* __restrict__ out)
{
  __shared__ float sWt[Hh][Dd];   // transposed ELM weights: sWt[h][d]
  __shared__ float sb[Hh];
  __shared__ __align__(16) float sWM[HP1][Tt];   // WM rows, broadcast b128 reads
  __shared__ float red[4][Tt];

  int tid = threadIdx.x;
  for (int i = tid; i < Dd * Hh; i += 256) sWt[i / Dd][i % Dd] = Welm[(i % Dd) * Hh + (i / Dd)];
  if (tid < Hh) sb[tid] = belm[tid];
  for (int i = tid; i < HP1 * Tt; i += 256) sWM[i / Tt][i % Tt] = wmT[i];
  __syncthreads();

  int n = blockIdx.x * 256 + tid;
  v16f acc = {};
  if (n < Nn) {
    const float4* xp = (const float4*)(Xd + (size_t)n * Dd);
    float4 x0 = xp[0], x1 = xp[1];
    float y = Yd[n];
    v16f pred = {};
#pragma unroll 8
    for (int h = 0; h < Hh; ++h) {
      float4 w0 = *(const float4*)&sWt[h][0];
      float4 w1 = *(const float4*)&sWt[h][4];
      float z = sb[h];
      z = fmaf(x0.x, w0.x, z); z = fmaf(x0.y, w0.y, z);
      z = fmaf(x0.z, w0.z, z); z = fmaf(x0.w, w0.w, z);
      z = fmaf(x1.x, w1.x, z); z = fmaf(x1.y, w1.y, z);
      z = fmaf(x1.z, w1.z, z); z = fmaf(x1.w, w1.w, z);
      float s = 1.f / (1.f + __expf(-z));
      const float4* wr = (const float4*)&sWM[h][0];   // LDS broadcast
      fma16(pred, s, wr[0], wr[1], wr[2], wr[3]);
    }
    { // bias feature (value 1) -> add WM row 40
      const float4* wr = (const float4*)&sWM[40][0];
      fma16(pred, 1.f, wr[0], wr[1], wr[2], wr[3]);
    }
    const float4* pp = (const float4*)(Phi + (size_t)n * Tt);
    float4 p0 = pp[0], p1 = pp[1], p2 = pp[2], p3 = pp[3];
    float ph[16] = {p0.x,p0.y,p0.z,p0.w, p1.x,p1.y,p1.z,p1.w,
                    p2.x,p2.y,p2.z,p2.w, p3.x,p3.y,p3.z,p3.w};
#pragma unroll
    for (int t = 0; t < Tt; ++t) {
      float e = y - pred[t];
      acc[t] = e * e * ph[t];
    }
  }
  // wave shuffle reduction, then cross-wave via LDS
#pragma unroll
  for (int t = 0; t < Tt; ++t) {
#pragma unroll
    for (int off = 32; off > 0; off >>= 1) acc[t] += __shfl_down(acc[t], off);
  }
  int wave = tid >> 6, lane = tid & 63;
  if (lane == 0) {
#pragma unroll
    for (int t = 0; t < Tt; ++t) red[wave][t] = acc[t];
  }
  __syncthreads();
  if (tid < Tt) {
    float s = red[0][tid] + red[1][tid] + red[2][tid] + red[3][tid];
    atomicAdd(&out[OFF_EB + tid], 0.5f * s);
  }
}

extern "C" void kernel_launch(void* const* d_in, const int* in_sizes, int n_in,
                              void* d_out, int out_size, void* d_ws, size_t ws_size,
                              hipStream_t stream) {
  const float* Phi = (const float*)d_in[1];
  const float* Xd  = (const float*)d_in[2];
  const float* Yd  = (const float*)d_in[3];
  const float* W   = (const float*)d_in[4];
  const float* bb  = (const float*)d_in[5];
  const float* eA  = (const float*)d_in[6];
  const float* eB  = (const float*)d_in[7];
  const float* zA  = (const float*)d_in[8];
  const float* zB  = (const float*)d_in[9];
  float* out = (float*)d_out;
  float* ws  = (float*)d_ws;

  float* acc_red = ws + WS_ACC;
  float* wmT     = ws + WS_WMT;
  float* part    = ws + WS_PART;
  float* slabs   = ws + WS_SLB;

  // slab count bounded by available scratch (deterministic, graph-safe)
  long avail = (long)(ws_size / 4) - WS_SLB;
  int grid1 = (int)(avail / SLAB);
  if (grid1 > NTILES) grid1 = NTILES;       // 782: one tile per block
  if (grid1 > MAXSLABS) grid1 = MAXSLABS;
  if (grid1 < 1) grid1 = 1;
  int ngrp = (grid1 + SLABGRP - 1) / SLABGRP;

  hipLaunchKernelGGL(gram_reduce, dim3(grid1), dim3(256), 0, stream, Phi, Xd, Yd, W, bb, slabs);
  hipLaunchKernelGGL(reduce_slabs_a, dim3(SLAB / 256, ngrp), dim3(256), 0, stream, slabs, grid1, part);
  hipLaunchKernelGGL(reduce_slabs_b, dim3(SLAB / 256), dim3(256), 0, stream, part, ngrp, acc_red);
  hipLaunchKernelGGL(finalize_kernel, dim3(Tt), dim3(64), 0, stream, acc_red, eA, eB, zA, zB, out, wmT);
  hipLaunchKernelGGL(resid_kernel, dim3((Nn + 255) / 256), dim3(256), 0, stream, Phi, Xd, Yd, W, bb, wmT, out);
}